// Round 13
// baseline (884.451 us; speedup 1.0000x reference)
//
#include <hip/hip_runtime.h>
#include <hip/hip_bf16.h>

#define NN 100000
#define EE 3200000
#define HH 64
#define H2 128
#define LL 3
#define GG 128
#define BN_EPSF 1e-5f

// CSR-build partition parameters
#define NBUK 782      // ceil(NN/128) buckets, bucket = dst >> 7
#define NBLKC 800     // partition blocks
#define CHUNK 4000    // edges per partition block (NBLKC*CHUNK == EE exactly)
#define DMAX 5120     // max edges per bucket (mean 4096, sd 64 -> 16 sigma)

static __device__ __forceinline__ float waveReduceSum64(float v){
  #pragma unroll
  for (int off = 32; off > 0; off >>= 1) v += __shfl_xor(v, off, 64);
  return v;
}

static __device__ __forceinline__ unsigned bf16rne(float f){
  unsigned u = __float_as_uint(f);
  return (u + 0x7FFFu + ((u >> 16) & 1u)) >> 16;
}

// accumulate 16 bf16 values (two uint4 = 8 words) into zacc[0..15]
static __device__ __forceinline__ void acc16(float* z, uint4 A, uint4 B){
  z[0]  += __uint_as_float(A.x << 16); z[1]  += __uint_as_float(A.x & 0xFFFF0000u);
  z[2]  += __uint_as_float(A.y << 16); z[3]  += __uint_as_float(A.y & 0xFFFF0000u);
  z[4]  += __uint_as_float(A.z << 16); z[5]  += __uint_as_float(A.z & 0xFFFF0000u);
  z[6]  += __uint_as_float(A.w << 16); z[7]  += __uint_as_float(A.w & 0xFFFF0000u);
  z[8]  += __uint_as_float(B.x << 16); z[9]  += __uint_as_float(B.x & 0xFFFF0000u);
  z[10] += __uint_as_float(B.y << 16); z[11] += __uint_as_float(B.y & 0xFFFF0000u);
  z[12] += __uint_as_float(B.z << 16); z[13] += __uint_as_float(B.z & 0xFFFF0000u);
  z[14] += __uint_as_float(B.w << 16); z[15] += __uint_as_float(B.w & 0xFFFF0000u);
}

// ================= CSR build: bucket-partitioned counting sort =================
// kA: per-block LDS histogram (int4 edge reads)
__global__ __launch_bounds__(256) void kA(const int* __restrict__ dst, int* __restrict__ cntmat){
  __shared__ int hist[NBUK];
  int t = threadIdx.x, blk = blockIdx.x;
  for (int j = t; j < NBUK; j += 256) hist[j] = 0;
  __syncthreads();
  const int4* d4 = (const int4*)(dst + blk * CHUNK);
  for (int i = t; i < CHUNK / 4; i += 256){
    int4 d = d4[i];
    atomicAdd(&hist[d.x >> 7], 1);
    atomicAdd(&hist[d.y >> 7], 1);
    atomicAdd(&hist[d.z >> 7], 1);
    atomicAdd(&hist[d.w >> 7], 1);
  }
  __syncthreads();
  for (int j = t; j < NBUK; j += 256) cntmat[j * NBLKC + blk] = hist[j];
}

__global__ __launch_bounds__(1024) void kB1(int* __restrict__ cntmat, int* __restrict__ btotal){
  __shared__ int s[1024];
  int t = threadIdx.x, j = blockIdx.x;
  int v = (t < NBLKC) ? cntmat[j * NBLKC + t] : 0;
  s[t] = v; __syncthreads();
  for (int off = 1; off < 1024; off <<= 1){
    int x = (t >= off) ? s[t - off] : 0; __syncthreads();
    s[t] += x; __syncthreads();
  }
  if (t < NBLKC) cntmat[j * NBLKC + t] = s[t] - v;   // exclusive prefix
  if (t == 1023) btotal[j] = s[t];
}

__global__ __launch_bounds__(1024) void kB2(const int* __restrict__ btotal,
                                            int* __restrict__ bucket_start,
                                            int* __restrict__ row_start){
  __shared__ int s[1024];
  int t = threadIdx.x;
  int v = (t < NBUK) ? btotal[t] : 0;
  s[t] = v; __syncthreads();
  for (int off = 1; off < 1024; off <<= 1){
    int x = (t >= off) ? s[t - off] : 0; __syncthreads();
    s[t] += x; __syncthreads();
  }
  if (t < NBUK) bucket_start[t] = s[t] - v;
  if (t == 0){ bucket_start[NBUK] = EE; row_start[NN] = EE; }
}

// kC: partition edges bucket-major; packed entry = src | (dloc << 17); int4 edge reads
__global__ __launch_bounds__(256) void kC(const int* __restrict__ src, const int* __restrict__ dst,
                                          const int* __restrict__ cntmat,
                                          const int* __restrict__ bucket_start,
                                          int* __restrict__ epart){
  __shared__ int off_s[NBUK];
  __shared__ int cur_s[NBUK];
  int t = threadIdx.x, blk = blockIdx.x;
  for (int j = t; j < NBUK; j += 256){
    off_s[j] = bucket_start[j] + cntmat[j * NBLKC + blk];
    cur_s[j] = 0;
  }
  __syncthreads();
  const int4* s4 = (const int4*)(src + blk * CHUNK);
  const int4* d4 = (const int4*)(dst + blk * CHUNK);
  for (int i = t; i < CHUNK / 4; i += 256){
    int4 s = s4[i];
    int4 d = d4[i];
    int j0 = d.x >> 7, j1 = d.y >> 7, j2 = d.z >> 7, j3 = d.w >> 7;
    int l0 = atomicAdd(&cur_s[j0], 1);
    epart[off_s[j0] + l0] = s.x | ((d.x & 127) << 17);
    int l1 = atomicAdd(&cur_s[j1], 1);
    epart[off_s[j1] + l1] = s.y | ((d.y & 127) << 17);
    int l2 = atomicAdd(&cur_s[j2], 1);
    epart[off_s[j2] + l2] = s.z | ((d.z & 127) << 17);
    int l3 = atomicAdd(&cur_s[j3], 1);
    epart[off_s[j3] + l3] = s.w | ((d.w & 127) << 17);
  }
}

__global__ __launch_bounds__(256) void kD(const int* __restrict__ epart,
                                          const int* __restrict__ bucket_start,
                                          int* __restrict__ row_start, int* __restrict__ elist){
  __shared__ int src_s[DMAX];
  __shared__ short dloc_s[DMAX];
  __shared__ int elist_s[DMAX];
  __shared__ int cnts[128];
  __shared__ int scan_s[128];
  int t = threadIdx.x, b = blockIdx.x;
  int bb = bucket_start[b], be = bucket_start[b + 1];
  int cnt = be - bb;
  int node_base = b << 7;
  if (t < 128) cnts[t] = 0;
  __syncthreads();
  for (int i = t; i < cnt; i += 256){
    int p = epart[bb + i];
    src_s[i] = p & 0x1FFFF;
    int dl = p >> 17;
    dloc_s[i] = (short)dl;
    atomicAdd(&cnts[dl], 1);
  }
  __syncthreads();
  if (t < 128) scan_s[t] = cnts[t];
  __syncthreads();
  for (int off = 1; off < 128; off <<= 1){
    int x = 0;
    if (t < 128 && t >= off) x = scan_s[t - off];
    __syncthreads();
    if (t < 128) scan_s[t] += x;
    __syncthreads();
  }
  if (t < 128){
    int e = scan_s[t] - cnts[t];          // exclusive prefix
    int node = node_base + t;
    if (node < NN) row_start[node] = bb + e;
    cnts[t] = e;                          // reuse as cursor
  }
  __syncthreads();
  for (int i = t; i < cnt; i += 256){
    int pos = atomicAdd(&cnts[(int)dloc_s[i]], 1);
    elist_s[pos] = src_s[i];
  }
  __syncthreads();
  for (int i = t; i < cnt; i += 256) elist[bb + i] = elist_s[i];
}

// ---------- gemm1 with fused gather; neighbors from bf16 hb; y1 written bf16:
// Zs[r][k] = (1+eps)*h[R][k] + sum_{e} hb[src_e][k]; y1 = bf16(Zs @ W1 + b1), fp32 col stats
__global__ __launch_bounds__(256, 4) void k_gemm1(const float* __restrict__ h,
                                                  const unsigned short* __restrict__ hb,
                                                  const int* __restrict__ row_start,
                                                  const int* __restrict__ elist,
                                                  const float* __restrict__ W1,
                                                  const float* __restrict__ b1,
                                                  const float* __restrict__ epsArr,
                                                  int layer,
                                                  unsigned short* __restrict__ y1b,
                                                  double* __restrict__ stats){
  alignas(16) __shared__ float Zs[64 * 64];    // [r][k]  16 KB
  __shared__ float redS[128];
  __shared__ float redQ[128];
  int t = threadIdx.x;
  int R0 = blockIdx.x * 64;
  float epsv = 1.0f + epsArr[layer];
  { // fused gather staging: 4 threads per row, 16 features per thread; edge loop unrolled x8
    int r  = t >> 2;            // 0..63
    int kq = (t & 3) * 16;      // feature-quarter base
    int R  = R0 + r;
    float zacc[16];
    if (R < NN){
      const float4* hr = (const float4*)&h[(long long)R * 64 + kq];
      #pragma unroll
      for (int i = 0; i < 4; ++i){
        float4 v = hr[i];
        zacc[4*i+0] = epsv * v.x; zacc[4*i+1] = epsv * v.y;
        zacc[4*i+2] = epsv * v.z; zacc[4*i+3] = epsv * v.w;
      }
      int beg = row_start[R], end = row_start[R + 1];
      int j = beg;
      for (; j + 7 < end; j += 8){
        int s0 = elist[j],   s1 = elist[j+1], s2 = elist[j+2], s3 = elist[j+3];
        int s4 = elist[j+4], s5 = elist[j+5], s6 = elist[j+6], s7 = elist[j+7];
        const uint4* q0 = (const uint4*)(hb + (size_t)s0 * 64 + kq);
        const uint4* q1 = (const uint4*)(hb + (size_t)s1 * 64 + kq);
        const uint4* q2 = (const uint4*)(hb + (size_t)s2 * 64 + kq);
        const uint4* q3 = (const uint4*)(hb + (size_t)s3 * 64 + kq);
        const uint4* q4 = (const uint4*)(hb + (size_t)s4 * 64 + kq);
        const uint4* q5 = (const uint4*)(hb + (size_t)s5 * 64 + kq);
        const uint4* q6 = (const uint4*)(hb + (size_t)s6 * 64 + kq);
        const uint4* q7 = (const uint4*)(hb + (size_t)s7 * 64 + kq);
        uint4 A0 = q0[0], B0 = q0[1];
        uint4 A1 = q1[0], B1 = q1[1];
        uint4 A2 = q2[0], B2 = q2[1];
        uint4 A3 = q3[0], B3 = q3[1];
        uint4 A4 = q4[0], B4 = q4[1];
        uint4 A5 = q5[0], B5 = q5[1];
        uint4 A6 = q6[0], B6 = q6[1];
        uint4 A7 = q7[0], B7 = q7[1];
        acc16(zacc, A0, B0); acc16(zacc, A1, B1);
        acc16(zacc, A2, B2); acc16(zacc, A3, B3);
        acc16(zacc, A4, B4); acc16(zacc, A5, B5);
        acc16(zacc, A6, B6); acc16(zacc, A7, B7);
      }
      for (; j < end; ++j){
        int s0 = elist[j];
        const uint4* q0 = (const uint4*)(hb + (size_t)s0 * 64 + kq);
        acc16(zacc, q0[0], q0[1]);
      }
    } else {
      #pragma unroll
      for (int i = 0; i < 16; ++i) zacc[i] = 0.f;
    }
    #pragma unroll
    for (int i = 0; i < 16; ++i) Zs[r * 64 + kq + i] = zacc[i];
  }
  __syncthreads();
  int c = t & 31, rg = t >> 5;
  int r0 = rg * 8;
  float a0[8], a1[8], a2[8], a3[8];
  #pragma unroll
  for (int r = 0; r < 8; ++r){ a0[r]=0.f; a1[r]=0.f; a2[r]=0.f; a3[r]=0.f; }
  for (int k4 = 0; k4 < 16; ++k4){
    float w0[4], w1[4], w2[4], w3[4];
    #pragma unroll
    for (int kk = 0; kk < 4; ++kk){
      int k = k4 * 4 + kk;
      w0[kk] = W1[k*128 + c];
      w1[kk] = W1[k*128 + c + 32];
      w2[kk] = W1[k*128 + c + 64];
      w3[kk] = W1[k*128 + c + 96];
    }
    #pragma unroll
    for (int r = 0; r < 8; ++r){
      float4 zv = *(const float4*)&Zs[(r0 + r) * 64 + k4 * 4];
      a0[r] += zv.x*w0[0] + zv.y*w0[1] + zv.z*w0[2] + zv.w*w0[3];
      a1[r] += zv.x*w1[0] + zv.y*w1[1] + zv.z*w1[2] + zv.w*w1[3];
      a2[r] += zv.x*w2[0] + zv.y*w2[1] + zv.z*w2[2] + zv.w*w2[3];
      a3[r] += zv.x*w3[0] + zv.y*w3[1] + zv.z*w3[2] + zv.w*w3[3];
    }
  }
  float b0 = b1[c], bb1 = b1[c+32], bb2 = b1[c+64], bb3 = b1[c+96];
  float s0=0,s1=0,s2=0,s3=0,q0=0,q1=0,q2=0,q3=0;
  #pragma unroll
  for (int r = 0; r < 8; ++r){
    int R = R0 + r0 + r;
    if (R < NN){
      float y0 = a0[r] + b0, yA = a1[r] + bb1, yB = a2[r] + bb2, yC = a3[r] + bb3;
      size_t base = (size_t)R * 128;
      y1b[base + c]      = (unsigned short)bf16rne(y0);
      y1b[base + c + 32] = (unsigned short)bf16rne(yA);
      y1b[base + c + 64] = (unsigned short)bf16rne(yB);
      y1b[base + c + 96] = (unsigned short)bf16rne(yC);
      s0 += y0; q0 += y0*y0; s1 += yA; q1 += yA*yA;
      s2 += yB; q2 += yB*yB; s3 += yC; q3 += yC*yC;
    }
  }
  __syncthreads();
  if (t < 128){ redS[t] = 0.f; redQ[t] = 0.f; }
  __syncthreads();
  atomicAdd(&redS[c],      s0); atomicAdd(&redQ[c],      q0);
  atomicAdd(&redS[c + 32], s1); atomicAdd(&redQ[c + 32], q1);
  atomicAdd(&redS[c + 64], s2); atomicAdd(&redQ[c + 64], q2);
  atomicAdd(&redS[c + 96], s3); atomicAdd(&redQ[c + 96], q3);
  __syncthreads();
  if (t < 128){
    atomicAdd(&stats[t],       (double)redS[t]);
    atomicAdd(&stats[128 + t], (double)redQ[t]);
  }
}

// ---------- gemm_k128: out[N,64] = act(in[N,128]) @ W[128,64] + b; W streamed from L2 ----------
// Also writes hb = bf16(relu(out)). mode&1: act=relu(in*scale+shift); mode&2: col stats;
// mode&4: input is bf16 (y1b), else fp32 (x).
__global__ __launch_bounds__(256, 4) void k_gemm_k128(const void* __restrict__ inRaw,
                                                      const float* __restrict__ W,
                                                      const float* __restrict__ b,
                                                      const float* __restrict__ bnp,
                                                      float* __restrict__ out,
                                                      unsigned short* __restrict__ hb,
                                                      double* __restrict__ stats,
                                                      int mode){
  alignas(16) __shared__ float As[64 * 128];   // [r][k]  32 KB
  __shared__ float redS[64];
  __shared__ float redQ[64];
  int t = threadIdx.x;
  int R0 = blockIdx.x * 64;
  { // stage A: 8 iters, each thread handles a 4-col group of a row
    #pragma unroll
    for (int i = 0; i < 8; ++i){
      int idx = t + i * 256;
      int r = idx >> 5;
      int kk = idx & 31;          // 4-col group index
      int R = R0 + r;
      float4 v = make_float4(0.f, 0.f, 0.f, 0.f);
      if (R < NN){
        if (mode & 4){
          uint2 u = ((const uint2*)inRaw)[(size_t)R * 32 + kk];
          v.x = __uint_as_float(u.x << 16);
          v.y = __uint_as_float(u.x & 0xFFFF0000u);
          v.z = __uint_as_float(u.y << 16);
          v.w = __uint_as_float(u.y & 0xFFFF0000u);
        } else {
          v = ((const float4*)inRaw)[(size_t)R * 32 + kk];
        }
        if (mode & 1){
          int k = kk * 4;
          v.x = fmaxf(v.x * bnp[k]   + bnp[128 + k],     0.f);
          v.y = fmaxf(v.y * bnp[k+1] + bnp[128 + k + 1], 0.f);
          v.z = fmaxf(v.z * bnp[k+2] + bnp[128 + k + 2], 0.f);
          v.w = fmaxf(v.w * bnp[k+3] + bnp[128 + k + 3], 0.f);
        }
      }
      *(float4*)&As[idx * 4] = v;
    }
  }
  __syncthreads();
  int c = t & 31, rg = t >> 5;
  int r0 = rg * 8;
  float a0[8], a1[8];
  #pragma unroll
  for (int r = 0; r < 8; ++r){ a0[r]=0.f; a1[r]=0.f; }
  for (int k4 = 0; k4 < 32; ++k4){
    float w0[4], w1[4];
    #pragma unroll
    for (int kk = 0; kk < 4; ++kk){
      int k = k4 * 4 + kk;
      w0[kk] = W[k*64 + c];
      w1[kk] = W[k*64 + c + 32];
    }
    #pragma unroll
    for (int r = 0; r < 8; ++r){
      float4 a = *(const float4*)&As[(r0 + r) * 128 + k4 * 4];
      a0[r] += a.x*w0[0] + a.y*w0[1] + a.z*w0[2] + a.w*w0[3];
      a1[r] += a.x*w1[0] + a.y*w1[1] + a.z*w1[2] + a.w*w1[3];
    }
  }
  float b0 = b[c], bA = b[c + 32];
  float s0=0,s1=0,q0=0,q1=0;
  #pragma unroll
  for (int r = 0; r < 8; ++r){
    int R = R0 + r0 + r;
    if (R < NN){
      float y0 = a0[r] + b0, yA = a1[r] + bA;
      long long base = (long long)R * 64;
      out[base + c] = y0;
      out[base + c + 32] = yA;
      hb[base + c]      = (unsigned short)bf16rne(fmaxf(y0, 0.f));
      hb[base + c + 32] = (unsigned short)bf16rne(fmaxf(yA, 0.f));
      s0 += y0; q0 += y0*y0; s1 += yA; q1 += yA*yA;
    }
  }
  if (mode & 2){
    __syncthreads();
    if (t < 64){ redS[t] = 0.f; redQ[t] = 0.f; }
    __syncthreads();
    atomicAdd(&redS[c], s0);      atomicAdd(&redQ[c], q0);
    atomicAdd(&redS[c + 32], s1); atomicAdd(&redQ[c + 32], q1);
    __syncthreads();
    if (t < 64){
      atomicAdd(&stats[t],      (double)redS[t]);
      atomicAdd(&stats[64 + t], (double)redQ[t]);
    }
  }
}

// ---------- bn finalize ----------
__global__ void k_bnfin(const double* __restrict__ stats, const float* __restrict__ gamma,
                        const float* __restrict__ beta, float* __restrict__ bnp, int C){
  int t = threadIdx.x;
  if (t < C){
    double s = stats[t], q = stats[C + t];
    double mu = s / (double)NN;
    double var = q / (double)NN - mu * mu;
    float rstd = rsqrtf((float)var + BN_EPSF);
    float sc = gamma[t] * rstd;
    bnp[t] = sc;
    bnp[C + t] = beta[t] - (float)mu * sc;
  }
}

// ---------- elementwise h = h*scale + shift; refresh hb = bf16(relu(h)) ----------
__global__ __launch_bounds__(256) void k_affine(float* __restrict__ h, unsigned short* __restrict__ hb,
                                                const float* __restrict__ bnp){
  int i = blockIdx.x * 256 + threadIdx.x;   // over N*16 float4 groups
  float4* h4 = (float4*)h;
  float4 v = h4[i];
  int base = (i * 4) & 63;
  v.x = v.x * bnp[base + 0] + bnp[64 + base + 0];
  v.y = v.y * bnp[base + 1] + bnp[64 + base + 1];
  v.z = v.z * bnp[base + 2] + bnp[64 + base + 2];
  v.w = v.w * bnp[base + 3] + bnp[64 + base + 3];
  h4[i] = v;
  unsigned w0 = bf16rne(fmaxf(v.x, 0.f)) | (bf16rne(fmaxf(v.y, 0.f)) << 16);
  unsigned w1 = bf16rne(fmaxf(v.z, 0.f)) | (bf16rne(fmaxf(v.w, 0.f)) << 16);
  int row = i >> 4;
  *(uint2*)(hb + (size_t)row * 64 + base) = make_uint2(w0, w1);
}

// ---------- gate + segmented segment-max over sorted batch ----------
__global__ __launch_bounds__(256) void k_gate(const float* __restrict__ h, const float* __restrict__ gateW,
                                              const float* __restrict__ gateB, const int* __restrict__ batch,
                                              float* __restrict__ gate, unsigned* __restrict__ gmaxkey){
  int lane = threadIdx.x & 63;
  int wid = blockIdx.x * 4 + (threadIdx.x >> 6);
  int nwaves = gridDim.x * 4;
  int chunk = (NN + nwaves - 1) / nwaves;
  int n0 = wid * chunk;
  int n1 = n0 + chunk; if (n1 > NN) n1 = NN;
  if (n0 >= NN) return;
  float gw = gateW[lane];
  float gb = gateB[0];
  int gcur = batch[n0];
  float mcur = -3.402823466e+38f;
  for (int n = n0; n < n1; ++n){
    int g = batch[n];
    if (g != gcur){
      if (lane == 0){
        unsigned u = __float_as_uint(mcur);
        u = (u & 0x80000000u) ? ~u : (u | 0x80000000u);
        atomicMax(&gmaxkey[gcur], u);
      }
      gcur = g;
      mcur = -3.402823466e+38f;
    }
    float v = h[(long long)n * 64 + lane] * gw;
    v = waveReduceSum64(v) + gb;   // all lanes hold v
    if (lane == 0) gate[n] = v;
    mcur = fmaxf(mcur, v);
  }
  if (lane == 0){
    unsigned u = __float_as_uint(mcur);
    u = (u & 0x80000000u) ? ~u : (u | 0x80000000u);
    atomicMax(&gmaxkey[gcur], u);
  }
}

// ---------- pooling: segmented accumulation over sorted batch ----------
__global__ __launch_bounds__(256) void k_pool(const float* __restrict__ h, const float* __restrict__ gate,
                                              const int* __restrict__ batch, const unsigned* __restrict__ gmaxkey,
                                              float* __restrict__ wsum, float* __restrict__ pooled){
  int lane = threadIdx.x & 63;
  int wid = blockIdx.x * 4 + (threadIdx.x >> 6);
  int nwaves = gridDim.x * 4;
  int chunk = (NN + nwaves - 1) / nwaves;
  int n0 = wid * chunk;
  int n1 = n0 + chunk; if (n1 > NN) n1 = NN;
  if (n0 >= NN) return;
  int gcur = batch[n0];
  unsigned u = gmaxkey[gcur];
  unsigned bits = (u & 0x80000000u) ? (u ^ 0x80000000u) : ~u;
  float m = __uint_as_float(bits);
  float acc = 0.f, wl = 0.f;
  for (int n = n0; n < n1; ++n){
    int g = batch[n];
    if (g != gcur){
      atomicAdd(&pooled[gcur * 64 + lane], acc);
      if (lane == 0) atomicAdd(&wsum[gcur], wl);
      gcur = g;
      u = gmaxkey[g];
      bits = (u & 0x80000000u) ? (u ^ 0x80000000u) : ~u;
      m = __uint_as_float(bits);
      acc = 0.f; wl = 0.f;
    }
    float w = expf(gate[n] - m);           // identical across lanes (broadcast loads)
    acc += w * h[(long long)n * 64 + lane];
    wl += w;
  }
  atomicAdd(&pooled[gcur * 64 + lane], acc);
  if (lane == 0) atomicAdd(&wsum[gcur], wl);
}

// ---------- head ----------
__global__ __launch_bounds__(64) void k_head(const float* __restrict__ pooled, const float* __restrict__ wsum,
                                             const float* __restrict__ predW, const float* __restrict__ predB,
                                             const float* __restrict__ clsW, const float* __restrict__ clsB,
                                             float* __restrict__ out){
  int g = blockIdx.x, lane = threadIdx.x;
  __shared__ float p[64];
  p[lane] = pooled[g * 64 + lane] / wsum[g];
  __syncthreads();
  float acc = predB[lane];
  for (int i = 0; i < 64; ++i) acc += p[i] * predW[i * 64 + lane];
  float z = fmaxf(acc, 0.f);
  float c0 = z * clsW[lane * 2 + 0];
  float c1 = z * clsW[lane * 2 + 1];
  c0 = waveReduceSum64(c0);
  c1 = waveReduceSum64(c1);
  if (lane == 0){
    out[g * 2 + 0] = c0 + clsB[0];
    out[g * 2 + 1] = c1 + clsB[1];
  }
}

extern "C" void kernel_launch(void* const* d_in, const int* in_sizes, int n_in,
                              void* d_out, int out_size, void* d_ws, size_t ws_size,
                              hipStream_t stream){
  const float* x     = (const float*)d_in[0];
  const float* lin0W = (const float*)d_in[1];
  const float* lin0b = (const float*)d_in[2];
  const float* eps   = (const float*)d_in[3];
  const float* W1    = (const float*)d_in[4];
  const float* b1    = (const float*)d_in[5];
  const float* g1    = (const float*)d_in[6];
  const float* be1   = (const float*)d_in[7];
  const float* W2    = (const float*)d_in[8];
  const float* b2    = (const float*)d_in[9];
  const float* gbn   = (const float*)d_in[10];
  const float* bbn   = (const float*)d_in[11];
  const float* gateW = (const float*)d_in[12];
  const float* gateB = (const float*)d_in[13];
  const float* predW = (const float*)d_in[14];
  const float* predB = (const float*)d_in[15];
  const float* clsW  = (const float*)d_in[16];
  const float* clsB  = (const float*)d_in[17];
  const int* eidx    = (const int*)d_in[18];
  const int* batch   = (const int*)d_in[19];
  const int* src = eidx;
  const int* dst = eidx + EE;
  float* out = (float*)d_out;

  // ---- workspace layout: EVERY sub-buffer 16B-aligned (R5 lesson) ----
  char* ws = (char*)d_ws;
  size_t off = 0;
  auto alloc = [&](size_t bytes) -> char* {
    char* p = ws + off;
    off += (bytes + 15) & ~(size_t)15;
    return p;
  };
  float* h       = (float*)alloc((size_t)NN * 64 * 4);                 // 25.6 MB
  unsigned short* y1b = (unsigned short*)alloc((size_t)NN * 128 * 2);  // 25.6 MB bf16
  int* elist     = (int*)alloc((size_t)EE * 4);                        // 12.8 MB
  unsigned short* hb = (unsigned short*)alloc((size_t)NN * 64 * 2);    // 12.8 MB bf16 shadow
  int* row_start = (int*)alloc((size_t)(NN + 1) * 4);
  float* gate    = (float*)alloc((size_t)NN * 4);
  double* stats1 = (double*)alloc(256 * 8);
  double* stats2 = (double*)alloc(128 * 8);
  float* bnp1    = (float*)alloc(256 * 4);
  float* bnp2    = (float*)alloc(128 * 4);
  unsigned* gmaxkey = (unsigned*)alloc(128 * 4);
  float* wsum    = (float*)alloc(128 * 4);
  float* pooled  = (float*)alloc(128 * 64 * 4);

  // CSR-build scratch OVERLAID inside y1b (dead until first k_gemm1 write).
  char* ov = (char*)y1b;
  int*  epart       = (int*)ov;                                    // 12.8 MB
  int*  cntmat      = (int*)(ov + (size_t)EE * 4);                 // 2.5 MB
  int*  btotal      = (int*)(ov + (size_t)EE * 4 + (size_t)NBUK * NBLKC * 4);
  int*  bucket_start= (int*)(ov + (size_t)EE * 4 + (size_t)NBUK * NBLKC * 4 + 3136);

  const int GBLK = (NN + 63) / 64;      // 1563 row-tiles

  // ---- CSR build: bucket-partitioned counting sort (coalesced writes) ----
  kA <<<NBLKC, 256, 0, stream>>>(dst, cntmat);
  kB1<<<NBUK, 1024, 0, stream>>>(cntmat, btotal);
  kB2<<<1, 1024, 0, stream>>>(btotal, bucket_start, row_start);
  kC <<<NBLKC, 256, 0, stream>>>(src, dst, cntmat, bucket_start, epart);
  kD <<<NBUK, 256, 0, stream>>>(epart, bucket_start, row_start, elist);

  // lin0: h = x @ lin0W + lin0b (fp32 input path; also writes hb shadow)
  k_gemm_k128<<<GBLK, 256, 0, stream>>>(x, lin0W, lin0b, bnp1, h, hb, stats2, 0);

  for (int l = 0; l < LL; ++l){
    hipMemsetAsync(stats1, 0, 256 * 8, stream);
    k_gemm1<<<GBLK, 256, 0, stream>>>(h, hb, row_start, elist, W1 + (size_t)l * 64 * 128,
                                      b1 + l * 128, eps, l, y1b, stats1);
    k_bnfin<<<1, 128, 0, stream>>>(stats1, g1 + l * 128, be1 + l * 128, bnp1, 128);
    if (l > 0) hipMemsetAsync(stats2, 0, 128 * 8, stream);
    int mode = 1 | 4 | (l > 0 ? 2 : 0);
    k_gemm_k128<<<GBLK, 256, 0, stream>>>(y1b, W2 + (size_t)l * 128 * 64, b2 + l * 64,
                                          bnp1, h, hb, stats2, mode);
    if (l > 0){
      k_bnfin<<<1, 64, 0, stream>>>(stats2, gbn + (l - 1) * 64, bbn + (l - 1) * 64, bnp2, 64);
      k_affine<<<(NN * 64 / 4) / 256, 256, 0, stream>>>(h, hb, bnp2);
    }
  }

  hipMemsetAsync(gmaxkey, 0, 128 * 4, stream);
  hipMemsetAsync(wsum, 0, 128 * 4, stream);
  hipMemsetAsync(pooled, 0, 128 * 64 * 4, stream);
  k_gate<<<1024, 256, 0, stream>>>(h, gateW, gateB, batch, gate, gmaxkey);
  k_pool<<<1024, 256, 0, stream>>>(h, gate, batch, gmaxkey, wsum, pooled);
  k_head<<<128, 64, 0, stream>>>(pooled, wsum, predW, predB, clsW, clsB, out);
}

// Round 14
// 859.748 us; speedup vs baseline: 1.0287x; 1.0287x over previous
//
#include <hip/hip_runtime.h>
#include <hip/hip_bf16.h>

#define NN 100000
#define EE 3200000
#define HH 64
#define H2 128
#define LL 3
#define GG 128
#define BN_EPSF 1e-5f

// CSR-build partition parameters
#define NBUK 782      // ceil(NN/128) buckets, bucket = dst >> 7
#define NBLKC 800     // partition blocks
#define CHUNK 4000    // edges per partition block (NBLKC*CHUNK == EE exactly)
#define DMAX 5120     // max edges per bucket (mean 4096, sd 64 -> 16 sigma)

static __device__ __forceinline__ float waveReduceSum64(float v){
  #pragma unroll
  for (int off = 32; off > 0; off >>= 1) v += __shfl_xor(v, off, 64);
  return v;
}

static __device__ __forceinline__ unsigned bf16rne(float f){
  unsigned u = __float_as_uint(f);
  return (u + 0x7FFFu + ((u >> 16) & 1u)) >> 16;
}

// accumulate 16 bf16 values (two uint4 = 8 words) into zacc[0..15]
static __device__ __forceinline__ void acc16(float* z, uint4 A, uint4 B){
  z[0]  += __uint_as_float(A.x << 16); z[1]  += __uint_as_float(A.x & 0xFFFF0000u);
  z[2]  += __uint_as_float(A.y << 16); z[3]  += __uint_as_float(A.y & 0xFFFF0000u);
  z[4]  += __uint_as_float(A.z << 16); z[5]  += __uint_as_float(A.z & 0xFFFF0000u);
  z[6]  += __uint_as_float(A.w << 16); z[7]  += __uint_as_float(A.w & 0xFFFF0000u);
  z[8]  += __uint_as_float(B.x << 16); z[9]  += __uint_as_float(B.x & 0xFFFF0000u);
  z[10] += __uint_as_float(B.y << 16); z[11] += __uint_as_float(B.y & 0xFFFF0000u);
  z[12] += __uint_as_float(B.z << 16); z[13] += __uint_as_float(B.z & 0xFFFF0000u);
  z[14] += __uint_as_float(B.w << 16); z[15] += __uint_as_float(B.w & 0xFFFF0000u);
}

// ================= CSR build: bucket-partitioned counting sort =================
__global__ __launch_bounds__(256) void kA(const int* __restrict__ dst, int* __restrict__ cntmat){
  __shared__ int hist[NBUK];
  int t = threadIdx.x, blk = blockIdx.x;
  for (int j = t; j < NBUK; j += 256) hist[j] = 0;
  __syncthreads();
  const int4* d4 = (const int4*)(dst + blk * CHUNK);
  for (int i = t; i < CHUNK / 4; i += 256){
    int4 d = d4[i];
    atomicAdd(&hist[d.x >> 7], 1);
    atomicAdd(&hist[d.y >> 7], 1);
    atomicAdd(&hist[d.z >> 7], 1);
    atomicAdd(&hist[d.w >> 7], 1);
  }
  __syncthreads();
  for (int j = t; j < NBUK; j += 256) cntmat[j * NBLKC + blk] = hist[j];
}

__global__ __launch_bounds__(1024) void kB1(int* __restrict__ cntmat, int* __restrict__ btotal){
  __shared__ int s[1024];
  int t = threadIdx.x, j = blockIdx.x;
  int v = (t < NBLKC) ? cntmat[j * NBLKC + t] : 0;
  s[t] = v; __syncthreads();
  for (int off = 1; off < 1024; off <<= 1){
    int x = (t >= off) ? s[t - off] : 0; __syncthreads();
    s[t] += x; __syncthreads();
  }
  if (t < NBLKC) cntmat[j * NBLKC + t] = s[t] - v;   // exclusive prefix
  if (t == 1023) btotal[j] = s[t];
}

__global__ __launch_bounds__(1024) void kB2(const int* __restrict__ btotal,
                                            int* __restrict__ bucket_start,
                                            int* __restrict__ row_start){
  __shared__ int s[1024];
  int t = threadIdx.x;
  int v = (t < NBUK) ? btotal[t] : 0;
  s[t] = v; __syncthreads();
  for (int off = 1; off < 1024; off <<= 1){
    int x = (t >= off) ? s[t - off] : 0; __syncthreads();
    s[t] += x; __syncthreads();
  }
  if (t < NBUK) bucket_start[t] = s[t] - v;
  if (t == 0){ bucket_start[NBUK] = EE; row_start[NN] = EE; }
}

// kC: partition edges bucket-major; packed entry = src | (dloc << 17); int4 edge reads
__global__ __launch_bounds__(256) void kC(const int* __restrict__ src, const int* __restrict__ dst,
                                          const int* __restrict__ cntmat,
                                          const int* __restrict__ bucket_start,
                                          int* __restrict__ epart){
  __shared__ int off_s[NBUK];
  __shared__ int cur_s[NBUK];
  int t = threadIdx.x, blk = blockIdx.x;
  for (int j = t; j < NBUK; j += 256){
    off_s[j] = bucket_start[j] + cntmat[j * NBLKC + blk];
    cur_s[j] = 0;
  }
  __syncthreads();
  const int4* s4 = (const int4*)(src + blk * CHUNK);
  const int4* d4 = (const int4*)(dst + blk * CHUNK);
  for (int i = t; i < CHUNK / 4; i += 256){
    int4 s = s4[i];
    int4 d = d4[i];
    int j0 = d.x >> 7, j1 = d.y >> 7, j2 = d.z >> 7, j3 = d.w >> 7;
    int l0 = atomicAdd(&cur_s[j0], 1);
    epart[off_s[j0] + l0] = s.x | ((d.x & 127) << 17);
    int l1 = atomicAdd(&cur_s[j1], 1);
    epart[off_s[j1] + l1] = s.y | ((d.y & 127) << 17);
    int l2 = atomicAdd(&cur_s[j2], 1);
    epart[off_s[j2] + l2] = s.z | ((d.z & 127) << 17);
    int l3 = atomicAdd(&cur_s[j3], 1);
    epart[off_s[j3] + l3] = s.w | ((d.w & 127) << 17);
  }
}

__global__ __launch_bounds__(256) void kD(const int* __restrict__ epart,
                                          const int* __restrict__ bucket_start,
                                          int* __restrict__ row_start, int* __restrict__ elist){
  __shared__ int src_s[DMAX];
  __shared__ short dloc_s[DMAX];
  __shared__ int elist_s[DMAX];
  __shared__ int cnts[128];
  __shared__ int scan_s[128];
  int t = threadIdx.x, b = blockIdx.x;
  int bb = bucket_start[b], be = bucket_start[b + 1];
  int cnt = be - bb;
  int node_base = b << 7;
  if (t < 128) cnts[t] = 0;
  __syncthreads();
  for (int i = t; i < cnt; i += 256){
    int p = epart[bb + i];
    src_s[i] = p & 0x1FFFF;
    int dl = p >> 17;
    dloc_s[i] = (short)dl;
    atomicAdd(&cnts[dl], 1);
  }
  __syncthreads();
  if (t < 128) scan_s[t] = cnts[t];
  __syncthreads();
  for (int off = 1; off < 128; off <<= 1){
    int x = 0;
    if (t < 128 && t >= off) x = scan_s[t - off];
    __syncthreads();
    if (t < 128) scan_s[t] += x;
    __syncthreads();
  }
  if (t < 128){
    int e = scan_s[t] - cnts[t];          // exclusive prefix
    int node = node_base + t;
    if (node < NN) row_start[node] = bb + e;
    cnts[t] = e;                          // reuse as cursor
  }
  __syncthreads();
  for (int i = t; i < cnt; i += 256){
    int pos = atomicAdd(&cnts[(int)dloc_s[i]], 1);
    elist_s[pos] = src_s[i];
  }
  __syncthreads();
  for (int i = t; i < cnt; i += 256) elist[bb + i] = elist_s[i];
}

// ---------- gemm1 with fused gather; degree-rank-balanced wave assignment:
// Zs[r][k] = (1+eps)*h[R][k] + sum_{e} hb[src_e][k]; y1 = bf16(Zs @ W1 + b1), fp32 col stats
__global__ __launch_bounds__(256, 4) void k_gemm1(const float* __restrict__ h,
                                                  const unsigned short* __restrict__ hb,
                                                  const int* __restrict__ row_start,
                                                  const int* __restrict__ elist,
                                                  const float* __restrict__ W1,
                                                  const float* __restrict__ b1,
                                                  const float* __restrict__ epsArr,
                                                  int layer,
                                                  unsigned short* __restrict__ y1b,
                                                  double* __restrict__ stats){
  alignas(16) __shared__ float Zs[64 * 64];    // [r][k]  16 KB
  __shared__ float redS[128];
  __shared__ float redQ[128];
  __shared__ int degS[64];
  __shared__ int permS[64];
  int t = threadIdx.x;
  int R0 = blockIdx.x * 64;
  float epsv = 1.0f + epsArr[layer];
  // degree-rank permutation: wave w handles ranks [16w,16w+16) -> near-equal degrees per wave
  if (t < 64){
    int R = R0 + t;
    degS[t] = (R < NN) ? (row_start[R + 1] - row_start[R]) : 0;
  }
  __syncthreads();
  if (t < 64){
    int d = degS[t];
    int rank = 0;
    #pragma unroll 8
    for (int r2 = 0; r2 < 64; ++r2){
      int d2 = degS[r2];
      rank += (d2 < d) || (d2 == d && r2 < t);
    }
    permS[rank] = t;
  }
  __syncthreads();
  { // fused gather staging: 4 threads per row, 16 features per thread; edge loop unrolled x4
    int r  = permS[t >> 2];     // physical row slot (degree-sorted assignment)
    int kq = (t & 3) * 16;      // feature-quarter base
    int R  = R0 + r;
    float zacc[16];
    if (R < NN){
      const float4* hr = (const float4*)&h[(long long)R * 64 + kq];
      #pragma unroll
      for (int i = 0; i < 4; ++i){
        float4 v = hr[i];
        zacc[4*i+0] = epsv * v.x; zacc[4*i+1] = epsv * v.y;
        zacc[4*i+2] = epsv * v.z; zacc[4*i+3] = epsv * v.w;
      }
      int beg = row_start[R], end = row_start[R + 1];
      int j = beg;
      for (; j + 3 < end; j += 4){
        int s0 = elist[j], s1 = elist[j+1], s2 = elist[j+2], s3 = elist[j+3];
        const uint4* q0 = (const uint4*)(hb + (size_t)s0 * 64 + kq);
        const uint4* q1 = (const uint4*)(hb + (size_t)s1 * 64 + kq);
        const uint4* q2 = (const uint4*)(hb + (size_t)s2 * 64 + kq);
        const uint4* q3 = (const uint4*)(hb + (size_t)s3 * 64 + kq);
        uint4 A0 = q0[0], B0 = q0[1];
        uint4 A1 = q1[0], B1 = q1[1];
        uint4 A2 = q2[0], B2 = q2[1];
        uint4 A3 = q3[0], B3 = q3[1];
        acc16(zacc, A0, B0); acc16(zacc, A1, B1);
        acc16(zacc, A2, B2); acc16(zacc, A3, B3);
      }
      for (; j < end; ++j){
        int s0 = elist[j];
        const uint4* q0 = (const uint4*)(hb + (size_t)s0 * 64 + kq);
        acc16(zacc, q0[0], q0[1]);
      }
    } else {
      #pragma unroll
      for (int i = 0; i < 16; ++i) zacc[i] = 0.f;
    }
    #pragma unroll
    for (int i = 0; i < 16; ++i) Zs[r * 64 + kq + i] = zacc[i];
  }
  __syncthreads();
  int c = t & 31, rg = t >> 5;
  int r0 = rg * 8;
  float a0[8], a1[8], a2[8], a3[8];
  #pragma unroll
  for (int r = 0; r < 8; ++r){ a0[r]=0.f; a1[r]=0.f; a2[r]=0.f; a3[r]=0.f; }
  for (int k4 = 0; k4 < 16; ++k4){
    float w0[4], w1[4], w2[4], w3[4];
    #pragma unroll
    for (int kk = 0; kk < 4; ++kk){
      int k = k4 * 4 + kk;
      w0[kk] = W1[k*128 + c];
      w1[kk] = W1[k*128 + c + 32];
      w2[kk] = W1[k*128 + c + 64];
      w3[kk] = W1[k*128 + c + 96];
    }
    #pragma unroll
    for (int r = 0; r < 8; ++r){
      float4 zv = *(const float4*)&Zs[(r0 + r) * 64 + k4 * 4];
      a0[r] += zv.x*w0[0] + zv.y*w0[1] + zv.z*w0[2] + zv.w*w0[3];
      a1[r] += zv.x*w1[0] + zv.y*w1[1] + zv.z*w1[2] + zv.w*w1[3];
      a2[r] += zv.x*w2[0] + zv.y*w2[1] + zv.z*w2[2] + zv.w*w2[3];
      a3[r] += zv.x*w3[0] + zv.y*w3[1] + zv.z*w3[2] + zv.w*w3[3];
    }
  }
  float b0 = b1[c], bb1 = b1[c+32], bb2 = b1[c+64], bb3 = b1[c+96];
  float s0=0,s1=0,s2=0,s3=0,q0=0,q1=0,q2=0,q3=0;
  #pragma unroll
  for (int r = 0; r < 8; ++r){
    int R = R0 + r0 + r;
    if (R < NN){
      float y0 = a0[r] + b0, yA = a1[r] + bb1, yB = a2[r] + bb2, yC = a3[r] + bb3;
      size_t base = (size_t)R * 128;
      y1b[base + c]      = (unsigned short)bf16rne(y0);
      y1b[base + c + 32] = (unsigned short)bf16rne(yA);
      y1b[base + c + 64] = (unsigned short)bf16rne(yB);
      y1b[base + c + 96] = (unsigned short)bf16rne(yC);
      s0 += y0; q0 += y0*y0; s1 += yA; q1 += yA*yA;
      s2 += yB; q2 += yB*yB; s3 += yC; q3 += yC*yC;
    }
  }
  __syncthreads();
  if (t < 128){ redS[t] = 0.f; redQ[t] = 0.f; }
  __syncthreads();
  atomicAdd(&redS[c],      s0); atomicAdd(&redQ[c],      q0);
  atomicAdd(&redS[c + 32], s1); atomicAdd(&redQ[c + 32], q1);
  atomicAdd(&redS[c + 64], s2); atomicAdd(&redQ[c + 64], q2);
  atomicAdd(&redS[c + 96], s3); atomicAdd(&redQ[c + 96], q3);
  __syncthreads();
  if (t < 128){
    atomicAdd(&stats[t],       (double)redS[t]);
    atomicAdd(&stats[128 + t], (double)redQ[t]);
  }
}

// ---------- gemm_k128: out[N,64] = act(in[N,128]) @ W[128,64] + b; W streamed from L2 ----------
// mode&1: act=relu(in*scale+shift); mode&2: col stats; mode&4: input bf16; mode&8: skip hb write
__global__ __launch_bounds__(256, 4) void k_gemm_k128(const void* __restrict__ inRaw,
                                                      const float* __restrict__ W,
                                                      const float* __restrict__ b,
                                                      const float* __restrict__ bnp,
                                                      float* __restrict__ out,
                                                      unsigned short* __restrict__ hb,
                                                      double* __restrict__ stats,
                                                      int mode){
  alignas(16) __shared__ float As[64 * 128];   // [r][k]  32 KB
  __shared__ float redS[64];
  __shared__ float redQ[64];
  int t = threadIdx.x;
  int R0 = blockIdx.x * 64;
  { // stage A: 8 iters, each thread handles a 4-col group of a row
    #pragma unroll
    for (int i = 0; i < 8; ++i){
      int idx = t + i * 256;
      int r = idx >> 5;
      int kk = idx & 31;          // 4-col group index
      int R = R0 + r;
      float4 v = make_float4(0.f, 0.f, 0.f, 0.f);
      if (R < NN){
        if (mode & 4){
          uint2 u = ((const uint2*)inRaw)[(size_t)R * 32 + kk];
          v.x = __uint_as_float(u.x << 16);
          v.y = __uint_as_float(u.x & 0xFFFF0000u);
          v.z = __uint_as_float(u.y << 16);
          v.w = __uint_as_float(u.y & 0xFFFF0000u);
        } else {
          v = ((const float4*)inRaw)[(size_t)R * 32 + kk];
        }
        if (mode & 1){
          int k = kk * 4;
          v.x = fmaxf(v.x * bnp[k]   + bnp[128 + k],     0.f);
          v.y = fmaxf(v.y * bnp[k+1] + bnp[128 + k + 1], 0.f);
          v.z = fmaxf(v.z * bnp[k+2] + bnp[128 + k + 2], 0.f);
          v.w = fmaxf(v.w * bnp[k+3] + bnp[128 + k + 3], 0.f);
        }
      }
      *(float4*)&As[idx * 4] = v;
    }
  }
  __syncthreads();
  int c = t & 31, rg = t >> 5;
  int r0 = rg * 8;
  float a0[8], a1[8];
  #pragma unroll
  for (int r = 0; r < 8; ++r){ a0[r]=0.f; a1[r]=0.f; }
  for (int k4 = 0; k4 < 32; ++k4){
    float w0[4], w1[4];
    #pragma unroll
    for (int kk = 0; kk < 4; ++kk){
      int k = k4 * 4 + kk;
      w0[kk] = W[k*64 + c];
      w1[kk] = W[k*64 + c + 32];
    }
    #pragma unroll
    for (int r = 0; r < 8; ++r){
      float4 a = *(const float4*)&As[(r0 + r) * 128 + k4 * 4];
      a0[r] += a.x*w0[0] + a.y*w0[1] + a.z*w0[2] + a.w*w0[3];
      a1[r] += a.x*w1[0] + a.y*w1[1] + a.z*w1[2] + a.w*w1[3];
    }
  }
  float b0 = b[c], bA = b[c + 32];
  float s0=0,s1=0,q0=0,q1=0;
  #pragma unroll
  for (int r = 0; r < 8; ++r){
    int R = R0 + r0 + r;
    if (R < NN){
      float y0 = a0[r] + b0, yA = a1[r] + bA;
      long long base = (long long)R * 64;
      out[base + c] = y0;
      out[base + c + 32] = yA;
      if (!(mode & 8)){
        hb[base + c]      = (unsigned short)bf16rne(fmaxf(y0, 0.f));
        hb[base + c + 32] = (unsigned short)bf16rne(fmaxf(yA, 0.f));
      }
      s0 += y0; q0 += y0*y0; s1 += yA; q1 += yA*yA;
    }
  }
  if (mode & 2){
    __syncthreads();
    if (t < 64){ redS[t] = 0.f; redQ[t] = 0.f; }
    __syncthreads();
    atomicAdd(&redS[c], s0);      atomicAdd(&redQ[c], q0);
    atomicAdd(&redS[c + 32], s1); atomicAdd(&redQ[c + 32], q1);
    __syncthreads();
    if (t < 64){
      atomicAdd(&stats[t],      (double)redS[t]);
      atomicAdd(&stats[64 + t], (double)redQ[t]);
    }
  }
}

// ---------- bn finalize ----------
__global__ void k_bnfin(const double* __restrict__ stats, const float* __restrict__ gamma,
                        const float* __restrict__ beta, float* __restrict__ bnp, int C){
  int t = threadIdx.x;
  if (t < C){
    double s = stats[t], q = stats[C + t];
    double mu = s / (double)NN;
    double var = q / (double)NN - mu * mu;
    float rstd = rsqrtf((float)var + BN_EPSF);
    float sc = gamma[t] * rstd;
    bnp[t] = sc;
    bnp[C + t] = beta[t] - (float)mu * sc;
  }
}

// ---------- elementwise h = h*scale + shift; refresh hb = bf16(relu(h)) ----------
__global__ __launch_bounds__(256) void k_affine(float* __restrict__ h, unsigned short* __restrict__ hb,
                                                const float* __restrict__ bnp){
  int i = blockIdx.x * 256 + threadIdx.x;   // over N*16 float4 groups
  float4* h4 = (float4*)h;
  float4 v = h4[i];
  int base = (i * 4) & 63;
  v.x = v.x * bnp[base + 0] + bnp[64 + base + 0];
  v.y = v.y * bnp[base + 1] + bnp[64 + base + 1];
  v.z = v.z * bnp[base + 2] + bnp[64 + base + 2];
  v.w = v.w * bnp[base + 3] + bnp[64 + base + 3];
  h4[i] = v;
  unsigned w0 = bf16rne(fmaxf(v.x, 0.f)) | (bf16rne(fmaxf(v.y, 0.f)) << 16);
  unsigned w1 = bf16rne(fmaxf(v.z, 0.f)) | (bf16rne(fmaxf(v.w, 0.f)) << 16);
  int row = i >> 4;
  *(uint2*)(hb + (size_t)row * 64 + base) = make_uint2(w0, w1);
}

// ---------- gate + segmented segment-max (applies fused BN affine to h) ----------
__global__ __launch_bounds__(256) void k_gate(const float* __restrict__ h, const float* __restrict__ gateW,
                                              const float* __restrict__ gateB, const int* __restrict__ batch,
                                              float* __restrict__ gate, unsigned* __restrict__ gmaxkey,
                                              const float* __restrict__ bnp){
  int lane = threadIdx.x & 63;
  int wid = blockIdx.x * 4 + (threadIdx.x >> 6);
  int nwaves = gridDim.x * 4;
  int chunk = (NN + nwaves - 1) / nwaves;
  int n0 = wid * chunk;
  int n1 = n0 + chunk; if (n1 > NN) n1 = NN;
  if (n0 >= NN) return;
  float sc = bnp[lane], sh = bnp[64 + lane];
  float gw = gateW[lane];
  float gb = gateB[0];
  int gcur = batch[n0];
  float mcur = -3.402823466e+38f;
  for (int n = n0; n < n1; ++n){
    int g = batch[n];
    if (g != gcur){
      if (lane == 0){
        unsigned u = __float_as_uint(mcur);
        u = (u & 0x80000000u) ? ~u : (u | 0x80000000u);
        atomicMax(&gmaxkey[gcur], u);
      }
      gcur = g;
      mcur = -3.402823466e+38f;
    }
    float hv = h[(long long)n * 64 + lane] * sc + sh;
    float v = hv * gw;
    v = waveReduceSum64(v) + gb;   // all lanes hold v
    if (lane == 0) gate[n] = v;
    mcur = fmaxf(mcur, v);
  }
  if (lane == 0){
    unsigned u = __float_as_uint(mcur);
    u = (u & 0x80000000u) ? ~u : (u | 0x80000000u);
    atomicMax(&gmaxkey[gcur], u);
  }
}

// ---------- pooling: segmented accumulation (applies fused BN affine to h) ----------
__global__ __launch_bounds__(256) void k_pool(const float* __restrict__ h, const float* __restrict__ gate,
                                              const int* __restrict__ batch, const unsigned* __restrict__ gmaxkey,
                                              float* __restrict__ wsum, float* __restrict__ pooled,
                                              const float* __restrict__ bnp){
  int lane = threadIdx.x & 63;
  int wid = blockIdx.x * 4 + (threadIdx.x >> 6);
  int nwaves = gridDim.x * 4;
  int chunk = (NN + nwaves - 1) / nwaves;
  int n0 = wid * chunk;
  int n1 = n0 + chunk; if (n1 > NN) n1 = NN;
  if (n0 >= NN) return;
  float sc = bnp[lane], sh = bnp[64 + lane];
  int gcur = batch[n0];
  unsigned u = gmaxkey[gcur];
  unsigned bits = (u & 0x80000000u) ? (u ^ 0x80000000u) : ~u;
  float m = __uint_as_float(bits);
  float acc = 0.f, wl = 0.f;
  for (int n = n0; n < n1; ++n){
    int g = batch[n];
    if (g != gcur){
      atomicAdd(&pooled[gcur * 64 + lane], acc);
      if (lane == 0) atomicAdd(&wsum[gcur], wl);
      gcur = g;
      u = gmaxkey[g];
      bits = (u & 0x80000000u) ? (u ^ 0x80000000u) : ~u;
      m = __uint_as_float(bits);
      acc = 0.f; wl = 0.f;
    }
    float w = expf(gate[n] - m);           // identical across lanes (broadcast loads)
    float hv = h[(long long)n * 64 + lane] * sc + sh;
    acc += w * hv;
    wl += w;
  }
  atomicAdd(&pooled[gcur * 64 + lane], acc);
  if (lane == 0) atomicAdd(&wsum[gcur], wl);
}

// ---------- head ----------
__global__ __launch_bounds__(64) void k_head(const float* __restrict__ pooled, const float* __restrict__ wsum,
                                             const float* __restrict__ predW, const float* __restrict__ predB,
                                             const float* __restrict__ clsW, const float* __restrict__ clsB,
                                             float* __restrict__ out){
  int g = blockIdx.x, lane = threadIdx.x;
  __shared__ float p[64];
  p[lane] = pooled[g * 64 + lane] / wsum[g];
  __syncthreads();
  float acc = predB[lane];
  for (int i = 0; i < 64; ++i) acc += p[i] * predW[i * 64 + lane];
  float z = fmaxf(acc, 0.f);
  float c0 = z * clsW[lane * 2 + 0];
  float c1 = z * clsW[lane * 2 + 1];
  c0 = waveReduceSum64(c0);
  c1 = waveReduceSum64(c1);
  if (lane == 0){
    out[g * 2 + 0] = c0 + clsB[0];
    out[g * 2 + 1] = c1 + clsB[1];
  }
}

extern "C" void kernel_launch(void* const* d_in, const int* in_sizes, int n_in,
                              void* d_out, int out_size, void* d_ws, size_t ws_size,
                              hipStream_t stream){
  const float* x     = (const float*)d_in[0];
  const float* lin0W = (const float*)d_in[1];
  const float* lin0b = (const float*)d_in[2];
  const float* eps   = (const float*)d_in[3];
  const float* W1    = (const float*)d_in[4];
  const float* b1    = (const float*)d_in[5];
  const float* g1    = (const float*)d_in[6];
  const float* be1   = (const float*)d_in[7];
  const float* W2    = (const float*)d_in[8];
  const float* b2    = (const float*)d_in[9];
  const float* gbn   = (const float*)d_in[10];
  const float* bbn   = (const float*)d_in[11];
  const float* gateW = (const float*)d_in[12];
  const float* gateB = (const float*)d_in[13];
  const float* predW = (const float*)d_in[14];
  const float* predB = (const float*)d_in[15];
  const float* clsW  = (const float*)d_in[16];
  const float* clsB  = (const float*)d_in[17];
  const int* eidx    = (const int*)d_in[18];
  const int* batch   = (const int*)d_in[19];
  const int* src = eidx;
  const int* dst = eidx + EE;
  float* out = (float*)d_out;

  // ---- workspace layout: EVERY sub-buffer 16B-aligned (R5 lesson) ----
  char* ws = (char*)d_ws;
  size_t off = 0;
  auto alloc = [&](size_t bytes) -> char* {
    char* p = ws + off;
    off += (bytes + 15) & ~(size_t)15;
    return p;
  };
  float* h       = (float*)alloc((size_t)NN * 64 * 4);                 // 25.6 MB
  unsigned short* y1b = (unsigned short*)alloc((size_t)NN * 128 * 2);  // 25.6 MB bf16
  int* elist     = (int*)alloc((size_t)EE * 4);                        // 12.8 MB
  unsigned short* hb = (unsigned short*)alloc((size_t)NN * 64 * 2);    // 12.8 MB bf16 shadow
  int* row_start = (int*)alloc((size_t)(NN + 1) * 4);
  float* gate    = (float*)alloc((size_t)NN * 4);
  double* stats1 = (double*)alloc(256 * 8);
  double* stats2 = (double*)alloc(128 * 8);
  float* bnp1    = (float*)alloc(256 * 4);
  float* bnp2    = (float*)alloc(128 * 4);
  unsigned* gmaxkey = (unsigned*)alloc(128 * 4);
  float* wsum    = (float*)alloc(128 * 4);
  float* pooled  = (float*)alloc(128 * 64 * 4);

  // CSR-build scratch OVERLAID inside y1b (dead until first k_gemm1 write).
  char* ov = (char*)y1b;
  int*  epart       = (int*)ov;                                    // 12.8 MB
  int*  cntmat      = (int*)(ov + (size_t)EE * 4);                 // 2.5 MB
  int*  btotal      = (int*)(ov + (size_t)EE * 4 + (size_t)NBUK * NBLKC * 4);
  int*  bucket_start= (int*)(ov + (size_t)EE * 4 + (size_t)NBUK * NBLKC * 4 + 3136);

  const int GBLK = (NN + 63) / 64;      // 1563 row-tiles

  // ---- CSR build: bucket-partitioned counting sort (coalesced writes) ----
  kA <<<NBLKC, 256, 0, stream>>>(dst, cntmat);
  kB1<<<NBUK, 1024, 0, stream>>>(cntmat, btotal);
  kB2<<<1, 1024, 0, stream>>>(btotal, bucket_start, row_start);
  kC <<<NBLKC, 256, 0, stream>>>(src, dst, cntmat, bucket_start, epart);
  kD <<<NBUK, 256, 0, stream>>>(epart, bucket_start, row_start, elist);

  // lin0: h = x @ lin0W + lin0b (fp32 input path; writes hb shadow for layer-0 gather)
  k_gemm_k128<<<GBLK, 256, 0, stream>>>(x, lin0W, lin0b, bnp1, h, hb, stats2, 0);

  for (int l = 0; l < LL; ++l){
    hipMemsetAsync(stats1, 0, 256 * 8, stream);
    k_gemm1<<<GBLK, 256, 0, stream>>>(h, hb, row_start, elist, W1 + (size_t)l * 64 * 128,
                                      b1 + l * 128, eps, l, y1b, stats1);
    k_bnfin<<<1, 128, 0, stream>>>(stats1, g1 + l * 128, be1 + l * 128, bnp1, 128);
    if (l > 0) hipMemsetAsync(stats2, 0, 128 * 8, stream);
    // hb write from k128 is only consumed when l==0 (later layers refresh via k_affine
    // or never read it again) -> mode&8 skips it for l>=1
    int mode = 1 | 4 | (l > 0 ? 2 : 0) | (l >= 1 ? 8 : 0);
    k_gemm_k128<<<GBLK, 256, 0, stream>>>(y1b, W2 + (size_t)l * 128 * 64, b2 + l * 64,
                                          bnp1, h, hb, stats2, mode);
    if (l > 0){
      k_bnfin<<<1, 64, 0, stream>>>(stats2, gbn + (l - 1) * 64, bbn + (l - 1) * 64, bnp2, 64);
      if (l < LL - 1)   // final affine is fused into k_gate/k_pool
        k_affine<<<(NN * 64 / 4) / 256, 256, 0, stream>>>(h, hb, bnp2);
    }
  }

  hipMemsetAsync(gmaxkey, 0, 128 * 4, stream);
  hipMemsetAsync(wsum, 0, 128 * 4, stream);
  hipMemsetAsync(pooled, 0, 128 * 64 * 4, stream);
  k_gate<<<1024, 256, 0, stream>>>(h, gateW, gateB, batch, gate, gmaxkey, bnp2);
  k_pool<<<1024, 256, 0, stream>>>(h, gate, batch, gmaxkey, wsum, pooled, bnp2);
  k_head<<<128, 64, 0, stream>>>(pooled, wsum, predW, predB, clsW, clsB, out);
}